// Round 5
// baseline (2874.768 us; speedup 1.0000x reference)
//
#include <hip/hip_runtime.h>
#include <hip/hip_bf16.h>

#define GN 16384
#define GD 128
#define KSPLIT 4
#define KBLK (GN / KSPLIT)        // 4096 k per block
#define BK 64                     // k per staged period
#define NPER (KBLK / BK)          // 64 periods
#define NPASS 8                   // measurement: repeat k-loop 8x, scale by 1/8
#define BUF_SHORTS (GD * BK)      // 8192 shorts = 16 KB per buffer
#define OUT_ELEMS (GN * GD)

typedef __attribute__((ext_vector_type(8))) short short8;
typedef __attribute__((ext_vector_type(4))) float floatx4;
typedef __attribute__((ext_vector_type(4))) int intx4;

static __device__ __forceinline__ unsigned short f32_to_bf16(float f) {
  unsigned u = __builtin_bit_cast(unsigned, f);
  unsigned r = u + 0x7FFFu + ((u >> 16) & 1u);  // RNE (inputs finite/normal)
  return (unsigned short)(r >> 16);
}

// Kernel 1: xT[d][j] <- bf16(x[j][d])
__global__ __launch_bounds__(256) void prep_kernel(const float* __restrict__ x,
                                                   unsigned short* __restrict__ xT) {
  __shared__ unsigned short t[GD][66];
  const int tid = threadIdx.x;
  const int j0 = blockIdx.x * 64;
  for (int i = tid; i < 64 * GD; i += 256) {
    int j = i >> 7, d = i & (GD - 1);
    t[d][j] = f32_to_bf16(x[(size_t)(j0 + j) * GD + d]);
  }
  __syncthreads();
  for (int i = tid; i < GD * 32; i += 256) {
    int d = i >> 5, jp = i & 31;
    unsigned lo = t[d][2 * jp], hi = t[d][2 * jp + 1];
    *reinterpret_cast<unsigned*>(xT + (size_t)d * GN + j0 + 2 * jp) = lo | (hi << 16);
  }
}

// Kernel 2: identical structure to R4, but (a) plain (non-nt) adj loads,
// (b) NPASS=8 identical passes accumulated then scaled by 0.125f (exact pow2) —
// pushes this dispatch into rocprof's top-5 so we finally get its counters.
__global__ __launch_bounds__(256, 4) void gemm_kernel(const int* __restrict__ adj,
                                                      const unsigned short* __restrict__ xT,
                                                      float* __restrict__ partials) {
  __shared__ unsigned short bbuf[2][BUF_SHORTS];
  const int tid = threadIdx.x;
  const int wave = tid >> 6;
  const int lane = tid & 63;
  const int q = lane >> 4;   // 0..3
  const int m = lane & 15;   // 0..15
  const int rbase = blockIdx.x * 64 + wave * 16;
  const int ks = blockIdx.y;
  const int kbase = ks * KBLK;

  const unsigned short* gptr[4];
  unsigned short* lptr[4];
#pragma unroll
  for (int p = 0; p < 4; ++p) {
    int s = tid + 256 * p;          // granule slot 0..1023
    int n = s >> 3;                 // B row (= d) 0..127
    int gsrc = (s & 7) ^ (n & 7);   // XOR swizzle (involution)
    gptr[p] = xT + (size_t)n * GN + kbase + gsrc * 8;
    lptr[p] = &bbuf[0][0] + (size_t)s * 8;
  }

#define STAGE(bufsel, koff)                                                             \
  do {                                                                                  \
    _Pragma("unroll") for (int p = 0; p < 4; ++p) {                                     \
      __builtin_amdgcn_global_load_lds(                                                 \
          (const __attribute__((address_space(1))) unsigned int*)(gptr[p] + (koff)),    \
          (__attribute__((address_space(3))) unsigned int*)(lptr[p] +                   \
                                                           (bufsel) * BUF_SHORTS),      \
          16, 0, 0);                                                                    \
    }                                                                                   \
  } while (0)

  const int* a0 = adj + (size_t)(rbase + m) * GN + kbase + q * 8;

  floatx4 acc[8];
#pragma unroll
  for (int c = 0; c < 8; ++c) acc[c] = (floatx4){0.f, 0.f, 0.f, 0.f};

  STAGE(0, 0);
  intx4 ca[4];
  ca[0] = *(const intx4*)(a0);
  ca[1] = *(const intx4*)(a0 + 4);
  ca[2] = *(const intx4*)(a0 + 32);
  ca[3] = *(const intx4*)(a0 + 36);

  int buf = 0;
  for (int pass = 0; pass < NPASS; ++pass) {
    for (int c = 0; c < NPER; ++c) {
      __syncthreads();  // staged buf ready; all waves done with buf^1
      const int nk = ((c + 1) & (NPER - 1)) * BK;  // wraps to k=0 at pass end
      if (!(pass == NPASS - 1 && c == NPER - 1)) STAGE(buf ^ 1, nk);
      intx4 na[4];
      na[0] = *(const intx4*)(a0 + nk);
      na[1] = *(const intx4*)(a0 + nk + 4);
      na[2] = *(const intx4*)(a0 + nk + 32);
      na[3] = *(const intx4*)(a0 + nk + 36);

#pragma unroll
      for (int kk = 0; kk < 2; ++kk) {
        short8 bf[8];
        const unsigned short* bb = &bbuf[buf][0] + ((4 * kk + q) ^ (m & 7)) * 8;
#pragma unroll
        for (int cc = 0; cc < 8; ++cc)
          bf[cc] = *(const short8*)(bb + (cc * 16 + m) * BK);

        const intx4 r0 = ca[2 * kk], r1 = ca[2 * kk + 1];
        intx4 pk;
        pk.x = (r0.x | (r0.y << 16)) * 0x3F80;
        pk.y = (r0.z | (r0.w << 16)) * 0x3F80;
        pk.z = (r1.x | (r1.y << 16)) * 0x3F80;
        pk.w = (r1.z | (r1.w << 16)) * 0x3F80;
        const short8 af = __builtin_bit_cast(short8, pk);

#pragma unroll
        for (int cc = 0; cc < 8; ++cc)
          acc[cc] = __builtin_amdgcn_mfma_f32_16x16x32_bf16(af, bf[cc], acc[cc], 0, 0, 0);
      }

#pragma unroll
      for (int u = 0; u < 4; ++u) ca[u] = na[u];
      buf ^= 1;
    }
  }

  // Epilogue: scale the 8-pass accumulation back (exact power of two).
  float* pp = partials + (size_t)ks * OUT_ELEMS + (size_t)rbase * GD;
#pragma unroll
  for (int cc = 0; cc < 8; ++cc)
#pragma unroll
    for (int r = 0; r < 4; ++r)
      pp[(size_t)(q * 4 + r) * GD + cc * 16 + m] = acc[cc][r] * 0.125f;
}

// Kernel 3: out = x + sum of 4 partials (also un-poisons d_out)
__global__ __launch_bounds__(256) void reduce_kernel(const float* __restrict__ x,
                                                     const float* __restrict__ partials,
                                                     float* __restrict__ out) {
  size_t i = ((size_t)blockIdx.x * 256 + threadIdx.x) * 4;
  floatx4 v = *(const floatx4*)(x + i);
  v += *(const floatx4*)(partials + 0 * (size_t)OUT_ELEMS + i);
  v += *(const floatx4*)(partials + 1 * (size_t)OUT_ELEMS + i);
  v += *(const floatx4*)(partials + 2 * (size_t)OUT_ELEMS + i);
  v += *(const floatx4*)(partials + 3 * (size_t)OUT_ELEMS + i);
  *(floatx4*)(out + i) = v;
}

extern "C" void kernel_launch(void* const* d_in, const int* in_sizes, int n_in,
                              void* d_out, int out_size, void* d_ws, size_t ws_size,
                              hipStream_t stream) {
  const float* x = (const float*)d_in[0];
  const int* adj = (const int*)d_in[1];
  float* out = (float*)d_out;
  unsigned short* xT = (unsigned short*)d_ws;                     // 4 MiB
  float* partials = (float*)((char*)d_ws + (size_t)GN * GD * 2);  // 4 x 8 MiB

  prep_kernel<<<GN / 64, 256, 0, stream>>>(x, xT);
  gemm_kernel<<<dim3(GN / 64, KSPLIT), 256, 0, stream>>>(adj, xT, partials);
  reduce_kernel<<<OUT_ELEMS / 4 / 256, 256, 0, stream>>>(x, partials, out);
}

// Round 6
// 1349.247 us; speedup vs baseline: 2.1306x; 2.1306x over previous
//
#include <hip/hip_runtime.h>
#include <hip/hip_bf16.h>

#define GN 16384
#define GD 128
#define KSPLIT 4
#define KBLK (GN / KSPLIT)        // 4096 k per block
#define PHK 128                   // k per LDS phase
#define NPH (KBLK / PHK)          // 32 phases
#define NSTEP (PHK / 32)          // 4 mfma k-steps per phase
#define BUF_SHORTS (GD * PHK)     // 16384 shorts = 32 KB per buffer
#define OUT_ELEMS (GN * GD)

typedef __attribute__((ext_vector_type(8))) short short8;
typedef __attribute__((ext_vector_type(4))) float floatx4;
typedef __attribute__((ext_vector_type(4))) int intx4;

static __device__ __forceinline__ unsigned short f32_to_bf16(float f) {
  unsigned u = __builtin_bit_cast(unsigned, f);
  unsigned r = u + 0x7FFFu + ((u >> 16) & 1u);  // RNE (inputs finite/normal)
  return (unsigned short)(r >> 16);
}

// Kernel 1: xT[d][j] <- bf16(x[j][d])  (4 MiB, L2/L3-resident)
__global__ __launch_bounds__(256) void prep_kernel(const float* __restrict__ x,
                                                   unsigned short* __restrict__ xT) {
  __shared__ unsigned short t[GD][66];
  const int tid = threadIdx.x;
  const int j0 = blockIdx.x * 64;
  for (int i = tid; i < 64 * GD; i += 256) {
    int j = i >> 7, d = i & (GD - 1);
    t[d][j] = f32_to_bf16(x[(size_t)(j0 + j) * GD + d]);
  }
  __syncthreads();
  for (int i = tid; i < GD * 32; i += 256) {
    int d = i >> 5, jp = i & 31;
    unsigned lo = t[d][2 * jp], hi = t[d][2 * jp + 1];
    *reinterpret_cast<unsigned*>(xT + (size_t)d * GN + j0 + 2 * jp) = lo | (hi << 16);
  }
}

// Kernel 2: partial[ks] = adj[128 rows, 4096-k slice] @ x  (bf16 MFMA, fp32 acc)
// 512 thr / 8 waves, BM=128 (16 rows/wave), BN=128, phase=128k double-buffered.
// Long phases amortize the vmcnt(0) barrier drain (R5's stall: one drain per 2KB
// of stream; now one per 8KB). 2 blocks/CU, 16 waves/CU.
// B LDS: row n (=d) holds 128 k = 256 B = 16 granules; slot gs of row n stores
// source granule gs^(n&7)  ->  frag ds_read_b128 spreads 8 bank-groups, 2-way (free).
__global__ __launch_bounds__(512, 4) void gemm_kernel(const int* __restrict__ adj,
                                                      const unsigned short* __restrict__ xT,
                                                      float* __restrict__ partials) {
  __shared__ unsigned short bbuf[2][BUF_SHORTS];  // 2 x 32 KB
  const int tid = threadIdx.x;
  const int wave = tid >> 6;
  const int lane = tid & 63;
  const int q = lane >> 4;   // 0..3
  const int m = lane & 15;   // 0..15
  const int rbase = blockIdx.x * 128 + wave * 16;
  const int ks = blockIdx.y;
  const int kbase = ks * KBLK;

  // staging: 4 granules (16 B) per thread; slot s = tid + 512p; row n = s>>4
  const unsigned short* gptr[4];
  unsigned short* lptr[4];
#pragma unroll
  for (int p = 0; p < 4; ++p) {
    int s = tid + 512 * p;            // 0..2047
    int n = s >> 4;                   // B row (= d) 0..127
    int gsrc = (s & 15) ^ (n & 7);    // XOR swizzle (involution on low 3 bits)
    gptr[p] = xT + (size_t)n * GN + kbase + gsrc * 8;
    lptr[p] = &bbuf[0][0] + (size_t)s * 8;
  }

#define STAGE(bufsel, koff)                                                             \
  do {                                                                                  \
    _Pragma("unroll") for (int p = 0; p < 4; ++p) {                                     \
      __builtin_amdgcn_global_load_lds(                                                 \
          (const __attribute__((address_space(1))) unsigned int*)(gptr[p] + (koff)),    \
          (__attribute__((address_space(3))) unsigned int*)(lptr[p] +                   \
                                                           (bufsel) * BUF_SHORTS),      \
          16, 0, 0);                                                                    \
    }                                                                                   \
  } while (0)

  const int* a0 = adj + (size_t)(rbase + m) * GN + kbase + q * 8;

  floatx4 acc[8];
#pragma unroll
  for (int c = 0; c < 8; ++c) acc[c] = (floatx4){0.f, 0.f, 0.f, 0.f};

  STAGE(0, 0);
  intx4 ca0 = *(const intx4*)(a0);
  intx4 ca1 = *(const intx4*)(a0 + 4);

  int buf = 0;
  for (int ph = 0; ph < NPH; ++ph) {
    __syncthreads();  // staged buf complete; all waves done with buf^1
    if (ph + 1 < NPH) STAGE(buf ^ 1, (ph + 1) * PHK);

#pragma unroll
    for (int st = 0; st < NSTEP; ++st) {
      const int g = ph * NSTEP + st;                     // global 32-k step 0..127
      const int nk = ((g + 1) & (KBLK / 32 - 1)) * 32;   // wraps on last (discarded)
      intx4 na0 = *(const intx4*)(a0 + nk);
      intx4 na1 = *(const intx4*)(a0 + nk + 4);

      // B frags: lane(q,m), col-tile cc -> row n=cc*16+m, granule (st*4+q)^(m&7)
      short8 bf[8];
      const unsigned short* bb = &bbuf[buf][0] + (((st * 4 + q) ^ (m & 7)) * 8);
#pragma unroll
      for (int cc = 0; cc < 8; ++cc)
        bf[cc] = *(const short8*)(bb + (cc * 16 + m) * PHK);

      // adj 0/1 int -> bf16 0x0000/0x3F80 (two elems per dword)
      intx4 pk;
      pk.x = (ca0.x | (ca0.y << 16)) * 0x3F80;
      pk.y = (ca0.z | (ca0.w << 16)) * 0x3F80;
      pk.z = (ca1.x | (ca1.y << 16)) * 0x3F80;
      pk.w = (ca1.z | (ca1.w << 16)) * 0x3F80;
      const short8 af = __builtin_bit_cast(short8, pk);

#pragma unroll
      for (int cc = 0; cc < 8; ++cc)
        acc[cc] = __builtin_amdgcn_mfma_f32_16x16x32_bf16(af, bf[cc], acc[cc], 0, 0, 0);

      ca0 = na0;
      ca1 = na1;
    }
    buf ^= 1;
  }

  // Epilogue: plain stores. C/D: col=lane&15, row=q*4+reg.
  float* pp = partials + (size_t)ks * OUT_ELEMS + (size_t)rbase * GD;
#pragma unroll
  for (int cc = 0; cc < 8; ++cc)
#pragma unroll
    for (int r = 0; r < 4; ++r)
      pp[(size_t)(q * 4 + r) * GD + cc * 16 + m] = acc[cc][r];
}

// Kernel 3: out = x + sum of 4 partials (also un-poisons d_out)
__global__ __launch_bounds__(256) void reduce_kernel(const float* __restrict__ x,
                                                     const float* __restrict__ partials,
                                                     float* __restrict__ out) {
  size_t i = ((size_t)blockIdx.x * 256 + threadIdx.x) * 4;
  floatx4 v = *(const floatx4*)(x + i);
  v += *(const floatx4*)(partials + 0 * (size_t)OUT_ELEMS + i);
  v += *(const floatx4*)(partials + 1 * (size_t)OUT_ELEMS + i);
  v += *(const floatx4*)(partials + 2 * (size_t)OUT_ELEMS + i);
  v += *(const floatx4*)(partials + 3 * (size_t)OUT_ELEMS + i);
  *(floatx4*)(out + i) = v;
}

extern "C" void kernel_launch(void* const* d_in, const int* in_sizes, int n_in,
                              void* d_out, int out_size, void* d_ws, size_t ws_size,
                              hipStream_t stream) {
  const float* x = (const float*)d_in[0];
  const int* adj = (const int*)d_in[1];
  float* out = (float*)d_out;
  unsigned short* xT = (unsigned short*)d_ws;                     // 4 MiB
  float* partials = (float*)((char*)d_ws + (size_t)GN * GD * 2);  // 4 x 8 MiB

  prep_kernel<<<GN / 64, 256, 0, stream>>>(x, xT);
  gemm_kernel<<<dim3(GN / 128, KSPLIT), 512, 0, stream>>>(adj, xT, partials);
  reduce_kernel<<<OUT_ELEMS / 4 / 256, 256, 0, stream>>>(x, partials, out);
}